// Round 20
// baseline (251.861 us; speedup 1.0000x reference)
//
// GraphSAGE MI355X — R20: biased-uint8 features + packed-u16 accumulation in
// agg (8 VALU ops/step vs 16; R19 agg was VALU-bound at 53% VALUBusy).
#include <hip/hip_runtime.h>

#define D 128
#define NBK_MAX 512
#define EPB 4096        // edges per bucket-count / binscatter block
#define BSLACK 1024     // per-bucket csr slack for ×4 padding

#define SX (6.0f / 127.0f)   // int8 scale for x  (N(0,1))
#define SH (8.0f / 127.0f)   // int8 scale for h

typedef __attribute__((ext_vector_type(4))) float f32x4;
typedef __attribute__((ext_vector_type(8))) short bf16x8;
typedef unsigned short ushort_t;
typedef unsigned int uint_t;
typedef unsigned char uchar_t;

__device__ inline ushort_t f2b(float f) {   // fp32 -> bf16 RNE
    uint_t u = __float_as_uint(f);
    u += 0x7FFF + ((u >> 16) & 1);
    return (ushort_t)(u >> 16);
}

// quantize 4 floats to BIASED uint8 (q+128, q in [-127,127]) packed in a dword
__device__ inline uint_t q8x4b(float a, float b, float c, float d, float inv_s) {
    int ra = (int)fminf(fmaxf(rintf(a * inv_s), -127.f), 127.f) + 128;
    int rb = (int)fminf(fmaxf(rintf(b * inv_s), -127.f), 127.f) + 128;
    int rc = (int)fminf(fmaxf(rintf(c * inv_s), -127.f), 127.f) + 128;
    int rd = (int)fminf(fmaxf(rintf(d * inv_s), -127.f), 127.f) + 128;
    return (uint_t)ra | ((uint_t)rb << 8) | ((uint_t)rc << 16) | ((uint_t)rd << 24);
}

// ===========================================================================
// Stage 0: per-bucket edge counts (LDS histogram; 391*391 global atomics).
// ===========================================================================
__global__ __launch_bounds__(256) void k_bucket_count(const int* __restrict__ ei,
                                                      int* __restrict__ bcnt,
                                                      int E, int nbk)
{
    __shared__ int hist[NBK_MAX];
    const int t = threadIdx.x;
    const int e0 = blockIdx.x * EPB;
    for (int i = t; i < nbk; i += 256) hist[i] = 0;
    __syncthreads();
    #pragma unroll
    for (int i = 0; i < 16; i++) {
        int e = e0 + i * 256 + t;
        if (e < E) atomicAdd(&hist[ei[E + e] >> 8], 1);
    }
    __syncthreads();
    for (int b = t; b < nbk; b += 256) {
        int c = hist[b];
        if (c) atomicAdd(&bcnt[b], c);
    }
}

__global__ __launch_bounds__(512) void k_scanb(const int* __restrict__ bcnt, int nbk,
                                               int* __restrict__ bbase,
                                               int* __restrict__ fill, int E)
{
    __shared__ int s[512];
    int t = threadIdx.x;
    int v = (t < nbk) ? bcnt[t] : 0;
    s[t] = v;
    __syncthreads();
    for (int o = 1; o < 512; o <<= 1) {
        int add = (t >= o) ? s[t - o] : 0;
        __syncthreads();
        s[t] += add;
        __syncthreads();
    }
    if (t < nbk) {
        int ex = s[t] - v;
        bbase[t] = ex;
        fill[t]  = ex;
    }
    if (t == 0) bbase[nbk] = E;
}

// ===========================================================================
// Stage 1: group edges by dst-bucket into eb (u32 {loc8<<24 | src24}).
// ===========================================================================
__global__ __launch_bounds__(256) void k_binscatter(const int* __restrict__ ei,
                                                    int* __restrict__ fill,
                                                    uint_t* __restrict__ eb,
                                                    int E, int nbk)
{
    __shared__ int hist[NBK_MAX];
    __shared__ int gbase[NBK_MAX];
    const int t = threadIdx.x;
    const int e0 = blockIdx.x * EPB;

    for (int i = t; i < nbk; i += 256) hist[i] = 0;
    __syncthreads();

    int src[16], dst[16], rank[16];
    #pragma unroll
    for (int i = 0; i < 16; i++) {
        int e = e0 + i * 256 + t;
        bool ok = (e < E);
        src[i]  = ok ? ei[e] : 0;
        dst[i]  = ok ? ei[E + e] : -1;
        rank[i] = ok ? atomicAdd(&hist[dst[i] >> 8], 1) : 0;
    }
    __syncthreads();
    for (int b = t; b < nbk; b += 256) {
        int c = hist[b];
        gbase[b] = c ? atomicAdd(&fill[b], c) : 0;
    }
    __syncthreads();
    #pragma unroll
    for (int i = 0; i < 16; i++) {
        if (dst[i] >= 0) {
            int pos = gbase[dst[i] >> 8] + rank[i];
            eb[pos] = ((uint_t)(dst[i] & 255) << 24) | (uint_t)src[i];
        }
    }
}

// ===========================================================================
// Stage 2: one block per bucket -> row_ptr (padded starts) + deg + csr_src
// (×4-padded with dummy row index).
// ===========================================================================
__global__ __launch_bounds__(256) void k_csr_fine(const uint_t* __restrict__ eb,
                                                  const int* __restrict__ bbase,
                                                  int* __restrict__ row_ptr,
                                                  int* __restrict__ deg,
                                                  int* __restrict__ csr_src,
                                                  int n, int dummy)
{
    __shared__ int s[256];
    __shared__ int pstart[256];
    __shared__ int hcnt[256];
    __shared__ int fl[256];
    const int b = blockIdx.x;
    const int t = threadIdx.x;
    const int base_eb  = bbase[b];
    const int cntb     = bbase[b + 1] - base_eb;
    const int base_csr = base_eb + BSLACK * b;

    hcnt[t] = 0; fl[t] = 0;
    __syncthreads();
    for (int i = t; i < cntb; i += 256)
        atomicAdd(&hcnt[eb[base_eb + i] >> 24], 1);
    __syncthreads();

    const int hc = hcnt[t];
    const int pc = (hc + 3) & ~3;
    s[t] = pc;
    __syncthreads();
    for (int o = 1; o < 256; o <<= 1) {
        int add = (t >= o) ? s[t - o] : 0;
        __syncthreads();
        s[t] += add;
        __syncthreads();
    }
    pstart[t] = s[t] - pc;
    int node = b * 256 + t;
    if (node < n) {
        row_ptr[node] = base_csr + pstart[t];
        deg[node] = hc;
    }
    __syncthreads();

    for (int i = t; i < cntb; i += 256) {
        uint_t e = eb[base_eb + i];
        int loc = (int)(e >> 24);
        int src = (int)(e & 0x00ffffffu);
        int off = pstart[loc] + atomicAdd(&fl[loc], 1);
        csr_src[base_csr + off] = src;
    }
    for (int k = hc; k < pc; k++)
        csr_src[base_csr + pstart[t] + k] = dummy;
}

// ===========================================================================
// cast: x -> biased uint8 xq; dummy rows of xq/hq = 0x80 (biased zero).
// ===========================================================================
__global__ __launch_bounds__(256) void k_cast_xq(const float* __restrict__ x,
                                                 uchar_t* __restrict__ xq,
                                                 uchar_t* __restrict__ hq,
                                                 int total8, int dummy)
{
    int i = blockIdx.x * 256 + threadIdx.x;   // one thread = 8 elems
    if (i < total8) {
        const float4* p = (const float4*)(x + (size_t)i * 8);
        float4 a = p[0], b = p[1];
        const float inv = 1.0f / SX;
        uint2 st;
        st.x = q8x4b(a.x, a.y, a.z, a.w, inv);
        st.y = q8x4b(b.x, b.y, b.z, b.w, inv);
        *(uint2*)(xq + (size_t)i * 8) = st;
    } else if (i < total8 + 32) {
        int k = i - total8;
        uchar_t* row = (k < 16 ? xq : hq);
        uint2 z = {0x80808080u, 0x80808080u};
        *(uint2*)(row + (size_t)dummy * D + (size_t)(k & 15) * 8) = z;
    }
}

// ===========================================================================
// weights -> FRAGMENT-ORDERED bf16:
// Wtf[((cb*8+kk)*64 + lane)*8 + e] = W_stacked[k][col],
//   col = cb*16 + (lane&15),  k = kk*32 + (lane>>4)*8 + e
// ===========================================================================
__global__ __launch_bounds__(256) void k_prep_wf(const float* __restrict__ W1l,
                                                 const float* __restrict__ W1r,
                                                 const float* __restrict__ W2l,
                                                 const float* __restrict__ W2r,
                                                 ushort_t* __restrict__ Wtf1,
                                                 ushort_t* __restrict__ Wtf2)
{
    int j = blockIdx.x * 256 + threadIdx.x;   // 0..4095 = (cb,kk,lane)
    if (j >= 8 * 8 * 64) return;
    int lane = j & 63;
    int kk   = (j >> 6) & 7;
    int cb   = j >> 9;
    int col  = cb * 16 + (lane & 15);
    int kbase = kk * 32 + (lane >> 4) * 8;
    ushort_t o1[8], o2[8];
    #pragma unroll
    for (int e = 0; e < 8; e++) {
        int k = kbase + e;
        float v1 = (k < D) ? W1l[(size_t)k * D + col] : W1r[(size_t)(k - D) * D + col];
        float v2 = (k < D) ? W2l[(size_t)k * D + col] : W2r[(size_t)(k - D) * D + col];
        o1[e] = f2b(v1);
        o2[e] = f2b(v2);
    }
    uint4 s1, s2;
    s1.x = (uint_t)o1[0] | ((uint_t)o1[1] << 16);
    s1.y = (uint_t)o1[2] | ((uint_t)o1[3] << 16);
    s1.z = (uint_t)o1[4] | ((uint_t)o1[5] << 16);
    s1.w = (uint_t)o1[6] | ((uint_t)o1[7] << 16);
    s2.x = (uint_t)o2[0] | ((uint_t)o2[1] << 16);
    s2.y = (uint_t)o2[2] | ((uint_t)o2[3] << 16);
    s2.z = (uint_t)o2[4] | ((uint_t)o2[5] << 16);
    s2.w = (uint_t)o2[6] | ((uint_t)o2[7] << 16);
    *(uint4*)(Wtf1 + (size_t)j * 8) = s1;
    *(uint4*)(Wtf2 + (size_t)j * 8) = s2;
}

// ===========================================================================
// Aggregation: one wave per dst node, biased-uint8 gather (128 B rows,
// 16 lanes/row, 4 subwarps -> 4 edges in flight). Packed-u16 accumulation:
// aA += r & 0x00ff00ff etc. -- 8 VALU/step vs 16 scalar. Capacity: <=16
// steps/chunk * 255 < 4096 per u16 lane (no carry crossing). Bias removed
// exactly: real = acc32 - 128*m_pad (int arithmetic, order-independent).
// ===========================================================================
__global__ __launch_bounds__(256) void k_agg_i8(const uchar_t* __restrict__ featq,
                                                const int* __restrict__ row_ptr,
                                                const int* __restrict__ deg,
                                                const int* __restrict__ csr_src,
                                                ushort_t* __restrict__ meanb,
                                                float scale, int n)
{
    int gtid = blockIdx.x * 256 + threadIdx.x;
    int v    = gtid >> 6;
    if (v >= n) return;
    int lane = threadIdx.x & 63;
    int sw   = lane >> 4;
    int sl   = lane & 15;

    const int beg = row_ptr[v];
    const int dg  = deg[v];
    const int m_pad = (dg + 3) & ~3;

    const uchar_t* fq = featq + sl * 8;
    int acc[8] = {0, 0, 0, 0, 0, 0, 0, 0};

    for (int base = 0; base < m_pad; base += 64) {
        int mchunk = m_pad - base; if (mchunk > 64) mchunk = 64;
        int id = csr_src[beg + base + lane];
        int steps = mchunk >> 2;
        uint_t aA = 0, aB = 0, aC = 0, aD = 0;
        #pragma unroll 4
        for (int t = 0; t < steps; t++) {
            int s = __shfl(id, sw + 4 * t);
            uint2 r = *(const uint2*)(fq + (size_t)s * D);
            aA += r.x & 0x00ff00ffu;
            aB += (r.x >> 8) & 0x00ff00ffu;
            aC += r.y & 0x00ff00ffu;
            aD += (r.y >> 8) & 0x00ff00ffu;
        }
        acc[0] += (int)(aA & 0xffffu); acc[2] += (int)(aA >> 16);
        acc[1] += (int)(aB & 0xffffu); acc[3] += (int)(aB >> 16);
        acc[4] += (int)(aC & 0xffffu); acc[6] += (int)(aC >> 16);
        acc[5] += (int)(aD & 0xffffu); acc[7] += (int)(aD >> 16);
    }

    #pragma unroll
    for (int q = 0; q < 8; q++) {
        acc[q] += __shfl_xor(acc[q], 16);
        acc[q] += __shfl_xor(acc[q], 32);
    }

    if (sw == 0) {
        // total bias: each of the m_pad entries (incl. dummy pads) adds 128
        // per column, and 4 subwarps' partials were summed -> the shfl_xor
        // reduce already combined them; bias per column = 128 * m_pad.
        const int bias = 128 * m_pad;
        float f = scale / fmaxf((float)dg, 1.0f);
        uint4 st;
        st.x = (uint_t)f2b((acc[0] - bias) * f) | ((uint_t)f2b((acc[1] - bias) * f) << 16);
        st.y = (uint_t)f2b((acc[2] - bias) * f) | ((uint_t)f2b((acc[3] - bias) * f) << 16);
        st.z = (uint_t)f2b((acc[4] - bias) * f) | ((uint_t)f2b((acc[5] - bias) * f) << 16);
        st.w = (uint_t)f2b((acc[6] - bias) * f) | ((uint_t)f2b((acc[7] - bias) * f) << 16);
        *(uint4*)(meanb + (size_t)v * D + sl * 8) = st;
    }
}

// ===========================================================================
// MFMA linear (operand-swapped, frag-ordered Wt): wave = 16 nodes x 128 cols.
// outq emits biased uint8 (consumed by layer-2 agg).
// ===========================================================================
__global__ __launch_bounds__(256) void k_linear_mfma(const ushort_t* __restrict__ meanb,
                                                     const ushort_t* __restrict__ xinb,
                                                     const float* __restrict__ xf,
                                                     const ushort_t* __restrict__ Wtf,
                                                     const float* __restrict__ bias,
                                                     float* __restrict__ outf,
                                                     ushort_t* __restrict__ outb,
                                                     uchar_t* __restrict__ outq,
                                                     int n, int npad, int relu)
{
    const int w    = threadIdx.x >> 6;
    const int lane = threadIdx.x & 63;
    const int kgrp = lane >> 4;             // 0..3
    const int l15  = lane & 15;
    const int tb   = blockIdx.x * 4 + w;    // 16-node tile index
    const int row  = tb * 16 + l15;         // this lane's node (B-frag row AND C row)
    if (tb * 16 >= npad) return;

    // B-frags: node features, k = kgrp*8 + kk*32 + e
    bf16x8 b[8];
    {
        const ushort_t* m0 = meanb + (size_t)row * D + kgrp * 8;
        #pragma unroll
        for (int kk = 0; kk < 4; kk++)
            b[kk] = *(const bf16x8*)(m0 + kk * 32);
        if (xf) {   // fp32 x source (layer 1): convert in-reg
            const float* x0 = xf + (size_t)min(row, n - 1) * D + kgrp * 8;
            #pragma unroll
            for (int kk = 0; kk < 4; kk++) {
                float4 p0 = *(const float4*)(x0 + kk * 32);
                float4 p1 = *(const float4*)(x0 + kk * 32 + 4);
                bf16x8 f;
                f[0] = (short)f2b(p0.x); f[1] = (short)f2b(p0.y);
                f[2] = (short)f2b(p0.z); f[3] = (short)f2b(p0.w);
                f[4] = (short)f2b(p1.x); f[5] = (short)f2b(p1.y);
                f[6] = (short)f2b(p1.z); f[7] = (short)f2b(p1.w);
                b[kk + 4] = f;
            }
        } else {    // bf16 source (layer 2)
            const ushort_t* x0 = xinb + (size_t)row * D + kgrp * 8;
            #pragma unroll
            for (int kk = 0; kk < 4; kk++)
                b[kk + 4] = *(const bf16x8*)(x0 + kk * 32);
        }
    }

    const bool ok = (row < n);
    const float invh = 1.0f / SH;
    #pragma unroll
    for (int cb = 0; cb < 8; cb++) {
        f32x4 acc = {0.f, 0.f, 0.f, 0.f};
        // A-frags: fragment-ordered, addr = (cb*512 + kk*64 + lane)*8 ushorts
        const ushort_t* wbase = Wtf + ((size_t)cb * 512 + lane) * 8;
        #pragma unroll
        for (int kk = 0; kk < 8; kk++) {
            bf16x8 a = *(const bf16x8*)(wbase + (size_t)kk * 64 * 8);
            acc = __builtin_amdgcn_mfma_f32_16x16x32_bf16(a, b[kk], acc, 0, 0, 0);
        }
        const int oc = cb * 16 + kgrp * 4;  // lane's 4 consecutive output cols
        float4 bv = *(const float4*)(bias + oc);
        float4 v;
        v.x = acc[0] + bv.x; v.y = acc[1] + bv.y;
        v.z = acc[2] + bv.z; v.w = acc[3] + bv.w;
        if (relu) {
            v.x = fmaxf(v.x, 0.f); v.y = fmaxf(v.y, 0.f);
            v.z = fmaxf(v.z, 0.f); v.w = fmaxf(v.w, 0.f);
        }
        if (ok) {
            if (outf) *(float4*)(outf + (size_t)row * D + oc) = v;
            if (outb) {
                uint2 st;
                st.x = (uint_t)f2b(v.x) | ((uint_t)f2b(v.y) << 16);
                st.y = (uint_t)f2b(v.z) | ((uint_t)f2b(v.w) << 16);
                *(uint2*)(outb + (size_t)row * D + oc) = st;
            }
            if (outq)
                *(uint_t*)(outq + (size_t)row * D + oc) = q8x4b(v.x, v.y, v.z, v.w, invh);
        }
    }
}

extern "C" void kernel_launch(void* const* d_in, const int* in_sizes, int n_in,
                              void* d_out, int out_size, void* d_ws, size_t ws_size,
                              hipStream_t stream)
{
    const float* x   = (const float*)d_in[0];
    const int*   ei  = (const int*)d_in[1];
    const float* W1l = (const float*)d_in[2];
    const float* b1  = (const float*)d_in[3];
    const float* W1r = (const float*)d_in[4];
    const float* W2l = (const float*)d_in[5];
    const float* b2  = (const float*)d_in[6];
    const float* W2r = (const float*)d_in[7];
    float* out = (float*)d_out;

    const int n = in_sizes[0] / D;   // 100000
    const int E = in_sizes[1] / 2;   // 1600000
    const int nbk = (n + 255) / 256; // 391 buckets
    const int tiles16 = (n + 15) / 16;               // 6250
    const int npad = tiles16 * 16;                   // 100000 == dummy row index

    // workspace layout (~92 MB; 102 MB proven OK in R1)
    size_t off = 0;
    auto alloc = [&](size_t bytes) { size_t o = off; off += (bytes + 511) & ~(size_t)511; return o; };
    char* ws = (char*)d_ws;
    int*      bcnt    = (int*)(ws + alloc((size_t)NBK_MAX * 4));
    int*      bbase   = (int*)(ws + alloc((size_t)(NBK_MAX + 1) * 4));
    int*      fill    = (int*)(ws + alloc((size_t)NBK_MAX * 4));
    int*      row_ptr = (int*)(ws + alloc((size_t)(n + 1) * 4));
    int*      deg     = (int*)(ws + alloc((size_t)n * 4));
    uint_t*   eb      = (uint_t*)(ws + alloc((size_t)E * 4));
    int*      csr_src = (int*)(ws + alloc(((size_t)E + (size_t)nbk * BSLACK + 64) * 4));
    ushort_t* meanb   = (ushort_t*)(ws + alloc((size_t)npad * D * 2));
    ushort_t* hb      = (ushort_t*)(ws + alloc((size_t)(npad + 1) * D * 2));
    uchar_t*  xq      = (uchar_t*)(ws + alloc((size_t)(npad + 1) * D));
    uchar_t*  hq      = (uchar_t*)(ws + alloc((size_t)(npad + 1) * D));
    ushort_t* Wtf1    = (ushort_t*)(ws + alloc((size_t)128 * 256 * 2));
    ushort_t* Wtf2    = (ushort_t*)(ws + alloc((size_t)128 * 256 * 2));

    hipMemsetAsync(bcnt, 0, (size_t)NBK_MAX * 4, stream);

    dim3 gB((E + EPB - 1) / EPB), gN(nbk);
    // CSR build (reused by both layers)
    k_bucket_count<<<gB, 256, 0, stream>>>(ei, bcnt, E, nbk);
    k_scanb       <<<1, 512, 0, stream>>>(bcnt, nbk, bbase, fill, E);
    k_binscatter  <<<gB, 256, 0, stream>>>(ei, fill, eb, E, nbk);
    k_csr_fine    <<<gN, 256, 0, stream>>>(eb, bbase, row_ptr, deg, csr_src, n, npad);

    // one-time casts (+ biased-zero dummy rows of xq/hq); fragment-ordered weights
    const int total8 = n * D / 8;
    k_cast_xq<<<dim3((total8 + 32 + 255) / 256), 256, 0, stream>>>(x, xq, hq, total8, npad);
    k_prep_wf<<<dim3(16), 256, 0, stream>>>(W1l, W1r, W2l, W2r, Wtf1, Wtf2);

    dim3 gAgg((n + 3) / 4);
    dim3 gLin((tiles16 + 3) / 4);   // 4 waves/block, 1 tile/wave

    // layer 1: agg gathers biased-uint8 x; linear B-x from fp32 x; emits hb + hq
    k_agg_i8     <<<gAgg, 256, 0, stream>>>(xq, row_ptr, deg, csr_src, meanb, SX, n);
    k_linear_mfma<<<gLin, 256, 0, stream>>>(meanb, (const ushort_t*)nullptr, x, Wtf1, b1,
                                            (float*)nullptr, hb, hq, n, npad, 1);

    // layer 2: agg gathers biased-uint8 h; linear B-x from bf16 hb; writes fp32 out
    k_agg_i8     <<<gAgg, 256, 0, stream>>>(hq, row_ptr, deg, csr_src, meanb, SH, n);
    k_linear_mfma<<<gLin, 256, 0, stream>>>(meanb, hb, (const float*)nullptr, Wtf2, b2,
                                            out, (ushort_t*)nullptr, (uchar_t*)nullptr, n, npad, 0);
}

// Round 21
// 228.122 us; speedup vs baseline: 1.1041x; 1.1041x over previous
//
// GraphSAGE MI355X — R21: subwarp-owns-node agg (no cross-subwarp reduce; the
// epilogue was ~40% of agg work) + lin1 x-side from xq (dequant in-reg).
#include <hip/hip_runtime.h>

#define D 128
#define NBK_MAX 512
#define EPB 4096        // edges per bucket-count / binscatter block

#define SX (6.0f / 127.0f)   // int8 scale for x  (N(0,1))
#define SH (8.0f / 127.0f)   // int8 scale for h

typedef __attribute__((ext_vector_type(4))) float f32x4;
typedef __attribute__((ext_vector_type(8))) short bf16x8;
typedef unsigned short ushort_t;
typedef unsigned int uint_t;
typedef unsigned char uchar_t;

__device__ inline ushort_t f2b(float f) {   // fp32 -> bf16 RNE
    uint_t u = __float_as_uint(f);
    u += 0x7FFF + ((u >> 16) & 1);
    return (ushort_t)(u >> 16);
}

// quantize 4 floats to BIASED uint8 (q+128, q in [-127,127]) packed in a dword
__device__ inline uint_t q8x4b(float a, float b, float c, float d, float inv_s) {
    int ra = (int)fminf(fmaxf(rintf(a * inv_s), -127.f), 127.f) + 128;
    int rb = (int)fminf(fmaxf(rintf(b * inv_s), -127.f), 127.f) + 128;
    int rc = (int)fminf(fmaxf(rintf(c * inv_s), -127.f), 127.f) + 128;
    int rd = (int)fminf(fmaxf(rintf(d * inv_s), -127.f), 127.f) + 128;
    return (uint_t)ra | ((uint_t)rb << 8) | ((uint_t)rc << 16) | ((uint_t)rd << 24);
}

// dequant 8 biased-uint8 (uint2) -> bf16x8 : val = (q-128)*SX
__device__ inline bf16x8 dq8(uint2 r) {
    bf16x8 o;
    #pragma unroll
    for (int e = 0; e < 4; e++) {
        float v0 = (float)(int)((r.x >> (8 * e)) & 0xffu) * SX - 128.0f * SX;
        float v1 = (float)(int)((r.y >> (8 * e)) & 0xffu) * SX - 128.0f * SX;
        o[e]     = (short)f2b(v0);
        o[e + 4] = (short)f2b(v1);
    }
    return o;
}

// ===========================================================================
// Stage 0: per-bucket edge counts (LDS histogram; 391*391 global atomics).
// ===========================================================================
__global__ __launch_bounds__(256) void k_bucket_count(const int* __restrict__ ei,
                                                      int* __restrict__ bcnt,
                                                      int E, int nbk)
{
    __shared__ int hist[NBK_MAX];
    const int t = threadIdx.x;
    const int e0 = blockIdx.x * EPB;
    for (int i = t; i < nbk; i += 256) hist[i] = 0;
    __syncthreads();
    #pragma unroll
    for (int i = 0; i < 16; i++) {
        int e = e0 + i * 256 + t;
        if (e < E) atomicAdd(&hist[ei[E + e] >> 8], 1);
    }
    __syncthreads();
    for (int b = t; b < nbk; b += 256) {
        int c = hist[b];
        if (c) atomicAdd(&bcnt[b], c);
    }
}

__global__ __launch_bounds__(512) void k_scanb(const int* __restrict__ bcnt, int nbk,
                                               int* __restrict__ bbase,
                                               int* __restrict__ fill, int E)
{
    __shared__ int s[512];
    int t = threadIdx.x;
    int v = (t < nbk) ? bcnt[t] : 0;
    s[t] = v;
    __syncthreads();
    for (int o = 1; o < 512; o <<= 1) {
        int add = (t >= o) ? s[t - o] : 0;
        __syncthreads();
        s[t] += add;
        __syncthreads();
    }
    if (t < nbk) {
        int ex = s[t] - v;
        bbase[t] = ex;
        fill[t]  = ex;
    }
    if (t == 0) bbase[nbk] = E;
}

// ===========================================================================
// Stage 1: group edges by dst-bucket into eb (u32 {loc8<<24 | src24}).
// ===========================================================================
__global__ __launch_bounds__(256) void k_binscatter(const int* __restrict__ ei,
                                                    int* __restrict__ fill,
                                                    uint_t* __restrict__ eb,
                                                    int E, int nbk)
{
    __shared__ int hist[NBK_MAX];
    __shared__ int gbase[NBK_MAX];
    const int t = threadIdx.x;
    const int e0 = blockIdx.x * EPB;

    for (int i = t; i < nbk; i += 256) hist[i] = 0;
    __syncthreads();

    int src[16], dst[16], rank[16];
    #pragma unroll
    for (int i = 0; i < 16; i++) {
        int e = e0 + i * 256 + t;
        bool ok = (e < E);
        src[i]  = ok ? ei[e] : 0;
        dst[i]  = ok ? ei[E + e] : -1;
        rank[i] = ok ? atomicAdd(&hist[dst[i] >> 8], 1) : 0;
    }
    __syncthreads();
    for (int b = t; b < nbk; b += 256) {
        int c = hist[b];
        gbase[b] = c ? atomicAdd(&fill[b], c) : 0;
    }
    __syncthreads();
    #pragma unroll
    for (int i = 0; i < 16; i++) {
        if (dst[i] >= 0) {
            int pos = gbase[dst[i] >> 8] + rank[i];
            eb[pos] = ((uint_t)(dst[i] & 255) << 24) | (uint_t)src[i];
        }
    }
}

// ===========================================================================
// Stage 2: one block per bucket -> row_ptr (exact starts) + deg + csr_src.
// No padding (the subwarp agg clamps per-lane).
// ===========================================================================
__global__ __launch_bounds__(256) void k_csr_fine(const uint_t* __restrict__ eb,
                                                  const int* __restrict__ bbase,
                                                  int* __restrict__ row_ptr,
                                                  int* __restrict__ deg,
                                                  int* __restrict__ csr_src,
                                                  int n)
{
    __shared__ int s[256];
    __shared__ int pstart[256];
    __shared__ int hcnt[256];
    __shared__ int fl[256];
    const int b = blockIdx.x;
    const int t = threadIdx.x;
    const int base_eb = bbase[b];
    const int cntb    = bbase[b + 1] - base_eb;

    hcnt[t] = 0; fl[t] = 0;
    __syncthreads();
    for (int i = t; i < cntb; i += 256)
        atomicAdd(&hcnt[eb[base_eb + i] >> 24], 1);
    __syncthreads();

    const int hc = hcnt[t];
    s[t] = hc;
    __syncthreads();
    for (int o = 1; o < 256; o <<= 1) {
        int add = (t >= o) ? s[t - o] : 0;
        __syncthreads();
        s[t] += add;
        __syncthreads();
    }
    pstart[t] = s[t] - hc;
    int node = b * 256 + t;
    if (node < n) {
        row_ptr[node] = base_eb + pstart[t];
        deg[node] = hc;
    }
    __syncthreads();

    for (int i = t; i < cntb; i += 256) {
        uint_t e = eb[base_eb + i];
        int loc = (int)(e >> 24);
        int src = (int)(e & 0x00ffffffu);
        int off = pstart[loc] + atomicAdd(&fl[loc], 1);
        csr_src[base_eb + off] = src;
    }
}

// ===========================================================================
// cast: x -> biased uint8 xq; dummy rows of xq/hq = 0x80 (biased zero).
// ===========================================================================
__global__ __launch_bounds__(256) void k_cast_xq(const float* __restrict__ x,
                                                 uchar_t* __restrict__ xq,
                                                 uchar_t* __restrict__ hq,
                                                 int total8, int dummy)
{
    int i = blockIdx.x * 256 + threadIdx.x;   // one thread = 8 elems
    if (i < total8) {
        const float4* p = (const float4*)(x + (size_t)i * 8);
        float4 a = p[0], b = p[1];
        const float inv = 1.0f / SX;
        uint2 st;
        st.x = q8x4b(a.x, a.y, a.z, a.w, inv);
        st.y = q8x4b(b.x, b.y, b.z, b.w, inv);
        *(uint2*)(xq + (size_t)i * 8) = st;
    } else if (i < total8 + 32) {
        int k = i - total8;
        uchar_t* row = (k < 16 ? xq : hq);
        uint2 z = {0x80808080u, 0x80808080u};
        *(uint2*)(row + (size_t)dummy * D + (size_t)(k & 15) * 8) = z;
    }
}

// ===========================================================================
// weights -> FRAGMENT-ORDERED bf16 (1 KB contiguous per A-frag load).
// ===========================================================================
__global__ __launch_bounds__(256) void k_prep_wf(const float* __restrict__ W1l,
                                                 const float* __restrict__ W1r,
                                                 const float* __restrict__ W2l,
                                                 const float* __restrict__ W2r,
                                                 ushort_t* __restrict__ Wtf1,
                                                 ushort_t* __restrict__ Wtf2)
{
    int j = blockIdx.x * 256 + threadIdx.x;   // 0..4095 = (cb,kk,lane)
    if (j >= 8 * 8 * 64) return;
    int lane = j & 63;
    int kk   = (j >> 6) & 7;
    int cb   = j >> 9;
    int col  = cb * 16 + (lane & 15);
    int kbase = kk * 32 + (lane >> 4) * 8;
    ushort_t o1[8], o2[8];
    #pragma unroll
    for (int e = 0; e < 8; e++) {
        int k = kbase + e;
        float v1 = (k < D) ? W1l[(size_t)k * D + col] : W1r[(size_t)(k - D) * D + col];
        float v2 = (k < D) ? W2l[(size_t)k * D + col] : W2r[(size_t)(k - D) * D + col];
        o1[e] = f2b(v1);
        o2[e] = f2b(v2);
    }
    uint4 s1, s2;
    s1.x = (uint_t)o1[0] | ((uint_t)o1[1] << 16);
    s1.y = (uint_t)o1[2] | ((uint_t)o1[3] << 16);
    s1.z = (uint_t)o1[4] | ((uint_t)o1[5] << 16);
    s1.w = (uint_t)o1[6] | ((uint_t)o1[7] << 16);
    s2.x = (uint_t)o2[0] | ((uint_t)o2[1] << 16);
    s2.y = (uint_t)o2[2] | ((uint_t)o2[3] << 16);
    s2.z = (uint_t)o2[4] | ((uint_t)o2[5] << 16);
    s2.w = (uint_t)o2[6] | ((uint_t)o2[7] << 16);
    *(uint4*)(Wtf1 + (size_t)j * 8) = s1;
    *(uint4*)(Wtf2 + (size_t)j * 8) = s2;
}

// ===========================================================================
// Aggregation (subwarp-owns-node): wave = 4 nodes; each 16-lane subwarp
// aggregates ONE node; lane sl holds cols sl*8..+7 (uint2 = 8 biased uint8)
// and accumulates them across all of its node's edges -> ZERO cross-lane
// reduce epilogue. All control wave-uniform: m4 = max deg of the 4 nodes;
// 16-edge chunks; OOB lanes carry DUMMY (biased-zero row, L1-hot); every
// __shfl runs on all 64 lanes. Packed-u16 accumulation (cap 16*255 per
// chunk); bias removed exactly: real = acc - 128*m4.
// ===========================================================================
__global__ __launch_bounds__(256) void k_agg_sub(const uchar_t* __restrict__ featq,
                                                 const int* __restrict__ row_ptr,
                                                 const int* __restrict__ deg,
                                                 const int* __restrict__ csr_src,
                                                 ushort_t* __restrict__ meanb,
                                                 float scale, int n, int dummy)
{
    const int lane = threadIdx.x & 63;
    const int sw   = lane >> 4;          // subwarp 0..3 -> node
    const int sl   = lane & 15;          // col group: cols sl*8..+7
    const int wbase = (blockIdx.x * 4 + (threadIdx.x >> 6)) * 4;  // 4 nodes/wave
    const int v = wbase + sw;
    if (wbase >= n) return;              // whole wave out (n % 4 == 0 here)

    const int vc  = min(v, n - 1);       // clamp (harmless dup if n%4 != 0)
    const int beg = row_ptr[vc];
    const int dg  = (v < n) ? deg[vc] : 0;

    // wave-uniform max degree of the 4 nodes
    int m4 = max(dg, __shfl_xor(dg, 16));
    m4 = max(m4, __shfl_xor(m4, 32));

    const uchar_t* fq = featq + sl * 8;
    int acc[8] = {0, 0, 0, 0, 0, 0, 0, 0};

    for (int base = 0; base < m4; base += 16) {
        int j  = base + sl;
        int cl = min(j, max(dg - 1, 0));
        int idr = csr_src[beg + cl];               // always in-bounds (slack)
        int id  = (j < dg) ? idr : dummy;
        int steps = min(16, m4 - base);            // wave-uniform
        uint_t aA = 0, aB = 0, aC = 0, aD = 0;
        #pragma unroll 4
        for (int t = 0; t < steps; t++) {
            int s = __shfl(id, (sw << 4) | t);     // all 64 lanes active
            uint2 r = *(const uint2*)(fq + (size_t)s * D);
            aA += r.x & 0x00ff00ffu;
            aB += (r.x >> 8) & 0x00ff00ffu;
            aC += r.y & 0x00ff00ffu;
            aD += (r.y >> 8) & 0x00ff00ffu;
        }
        acc[0] += (int)(aA & 0xffffu); acc[2] += (int)(aA >> 16);
        acc[1] += (int)(aB & 0xffffu); acc[3] += (int)(aB >> 16);
        acc[4] += (int)(aC & 0xffffu); acc[6] += (int)(aC >> 16);
        acc[5] += (int)(aD & 0xffffu); acc[7] += (int)(aD >> 16);
    }

    if (v < n) {
        const int bias = 128 * m4;     // every step contributes +128/byte-lane
        float f = scale / fmaxf((float)dg, 1.0f);
        uint4 st;
        st.x = (uint_t)f2b((acc[0] - bias) * f) | ((uint_t)f2b((acc[1] - bias) * f) << 16);
        st.y = (uint_t)f2b((acc[2] - bias) * f) | ((uint_t)f2b((acc[3] - bias) * f) << 16);
        st.z = (uint_t)f2b((acc[4] - bias) * f) | ((uint_t)f2b((acc[5] - bias) * f) << 16);
        st.w = (uint_t)f2b((acc[6] - bias) * f) | ((uint_t)f2b((acc[7] - bias) * f) << 16);
        *(uint4*)(meanb + (size_t)v * D + sl * 8) = st;
    }
}

// ===========================================================================
// MFMA linear (operand-swapped, frag-ordered Wt): wave = 16 nodes x 128 cols.
// x-side B-frags from biased-uint8 xqf (lin1, dequant in-reg) or bf16 xinb
// (lin2). outq emits biased uint8.
// ===========================================================================
__global__ __launch_bounds__(256) void k_linear_mfma(const ushort_t* __restrict__ meanb,
                                                     const ushort_t* __restrict__ xinb,
                                                     const uchar_t* __restrict__ xqf,
                                                     const ushort_t* __restrict__ Wtf,
                                                     const float* __restrict__ bias,
                                                     float* __restrict__ outf,
                                                     ushort_t* __restrict__ outb,
                                                     uchar_t* __restrict__ outq,
                                                     int n, int npad, int relu)
{
    const int w    = threadIdx.x >> 6;
    const int lane = threadIdx.x & 63;
    const int kgrp = lane >> 4;             // 0..3
    const int l15  = lane & 15;
    const int tb   = blockIdx.x * 4 + w;    // 16-node tile index
    const int row  = tb * 16 + l15;
    if (tb * 16 >= npad) return;

    bf16x8 b[8];
    {
        const ushort_t* m0 = meanb + (size_t)row * D + kgrp * 8;
        #pragma unroll
        for (int kk = 0; kk < 4; kk++)
            b[kk] = *(const bf16x8*)(m0 + kk * 32);
        if (xqf) {  // biased-uint8 x source (layer 1): dequant in-reg
            const uchar_t* x0 = xqf + (size_t)min(row, n - 1) * D + kgrp * 8;
            #pragma unroll
            for (int kk = 0; kk < 4; kk++)
                b[kk + 4] = dq8(*(const uint2*)(x0 + kk * 32));
        } else {    // bf16 source (layer 2)
            const ushort_t* x0 = xinb + (size_t)row * D + kgrp * 8;
            #pragma unroll
            for (int kk = 0; kk < 4; kk++)
                b[kk + 4] = *(const bf16x8*)(x0 + kk * 32);
        }
    }

    const bool ok = (row < n);
    const float invh = 1.0f / SH;
    #pragma unroll
    for (int cb = 0; cb < 8; cb++) {
        f32x4 acc = {0.f, 0.f, 0.f, 0.f};
        const ushort_t* wbase = Wtf + ((size_t)cb * 512 + lane) * 8;
        #pragma unroll
        for (int kk = 0; kk < 8; kk++) {
            bf16x8 a = *(const bf16x8*)(wbase + (size_t)kk * 64 * 8);
            acc = __builtin_amdgcn_mfma_f32_16x16x32_bf16(a, b[kk], acc, 0, 0, 0);
        }
        const int oc = cb * 16 + kgrp * 4;
        float4 bv = *(const float4*)(bias + oc);
        float4 v;
        v.x = acc[0] + bv.x; v.y = acc[1] + bv.y;
        v.z = acc[2] + bv.z; v.w = acc[3] + bv.w;
        if (relu) {
            v.x = fmaxf(v.x, 0.f); v.y = fmaxf(v.y, 0.f);
            v.z = fmaxf(v.z, 0.f); v.w = fmaxf(v.w, 0.f);
        }
        if (ok) {
            if (outf) *(float4*)(outf + (size_t)row * D + oc) = v;
            if (outb) {
                uint2 st;
                st.x = (uint_t)f2b(v.x) | ((uint_t)f2b(v.y) << 16);
                st.y = (uint_t)f2b(v.z) | ((uint_t)f2b(v.w) << 16);
                *(uint2*)(outb + (size_t)row * D + oc) = st;
            }
            if (outq)
                *(uint_t*)(outq + (size_t)row * D + oc) = q8x4b(v.x, v.y, v.z, v.w, invh);
        }
    }
}

extern "C" void kernel_launch(void* const* d_in, const int* in_sizes, int n_in,
                              void* d_out, int out_size, void* d_ws, size_t ws_size,
                              hipStream_t stream)
{
    const float* x   = (const float*)d_in[0];
    const int*   ei  = (const int*)d_in[1];
    const float* W1l = (const float*)d_in[2];
    const float* b1  = (const float*)d_in[3];
    const float* W1r = (const float*)d_in[4];
    const float* W2l = (const float*)d_in[5];
    const float* b2  = (const float*)d_in[6];
    const float* W2r = (const float*)d_in[7];
    float* out = (float*)d_out;

    const int n = in_sizes[0] / D;   // 100000
    const int E = in_sizes[1] / 2;   // 1600000
    const int nbk = (n + 255) / 256; // 391 buckets
    const int tiles16 = (n + 15) / 16;               // 6250
    const int npad = tiles16 * 16;                   // 100000 == dummy row index

    // workspace layout (~88 MB; 102 MB proven OK in R1)
    size_t off = 0;
    auto alloc = [&](size_t bytes) { size_t o = off; off += (bytes + 511) & ~(size_t)511; return o; };
    char* ws = (char*)d_ws;
    int*      bcnt    = (int*)(ws + alloc((size_t)NBK_MAX * 4));
    int*      bbase   = (int*)(ws + alloc((size_t)(NBK_MAX + 1) * 4));
    int*      fill    = (int*)(ws + alloc((size_t)NBK_MAX * 4));
    int*      row_ptr = (int*)(ws + alloc((size_t)(n + 1) * 4));
    int*      deg     = (int*)(ws + alloc((size_t)n * 4));
    uint_t*   eb      = (uint_t*)(ws + alloc((size_t)E * 4));
    int*      csr_src = (int*)(ws + alloc(((size_t)E + 64) * 4));
    ushort_t* meanb   = (ushort_t*)(ws + alloc((size_t)npad * D * 2));
    ushort_t* hb      = (ushort_t*)(ws + alloc((size_t)(npad + 1) * D * 2));
    uchar_t*  xq      = (uchar_t*)(ws + alloc((size_t)(npad + 1) * D));
    uchar_t*  hq      = (uchar_t*)(ws + alloc((size_t)(npad + 1) * D));
    ushort_t* Wtf1    = (ushort_t*)(ws + alloc((size_t)128 * 256 * 2));
    ushort_t* Wtf2    = (ushort_t*)(ws + alloc((size_t)128 * 256 * 2));

    hipMemsetAsync(bcnt, 0, (size_t)NBK_MAX * 4, stream);

    dim3 gB((E + EPB - 1) / EPB), gN(nbk);
    // CSR build (reused by both layers)
    k_bucket_count<<<gB, 256, 0, stream>>>(ei, bcnt, E, nbk);
    k_scanb       <<<1, 512, 0, stream>>>(bcnt, nbk, bbase, fill, E);
    k_binscatter  <<<gB, 256, 0, stream>>>(ei, fill, eb, E, nbk);
    k_csr_fine    <<<gN, 256, 0, stream>>>(eb, bbase, row_ptr, deg, csr_src, n);

    // one-time casts (+ biased-zero dummy rows of xq/hq); fragment-ordered weights
    const int total8 = n * D / 8;
    k_cast_xq<<<dim3((total8 + 32 + 255) / 256), 256, 0, stream>>>(x, xq, hq, total8, npad);
    k_prep_wf<<<dim3(16), 256, 0, stream>>>(W1l, W1r, W2l, W2r, Wtf1, Wtf2);

    dim3 gAgg((n + 15) / 16);       // 4 waves/block, 4 nodes/wave
    dim3 gLin((tiles16 + 3) / 4);   // 4 waves/block, 1 tile/wave

    // layer 1: agg gathers biased-uint8 x; lin x-side from xq; emits hb + hq
    k_agg_sub    <<<gAgg, 256, 0, stream>>>(xq, row_ptr, deg, csr_src, meanb, SX, n, npad);
    k_linear_mfma<<<gLin, 256, 0, stream>>>(meanb, (const ushort_t*)nullptr, xq, Wtf1, b1,
                                            (float*)nullptr, hb, hq, n, npad, 1);

    // layer 2: agg gathers biased-uint8 h; lin x-side from bf16 hb; writes fp32 out
    k_agg_sub    <<<gAgg, 256, 0, stream>>>(hq, row_ptr, deg, csr_src, meanb, SH, n, npad);
    k_linear_mfma<<<gLin, 256, 0, stream>>>(meanb, hb, (const uchar_t*)nullptr, Wtf2, b2,
                                            out, (ushort_t*)nullptr, (uchar_t*)nullptr, n, npad, 0);
}